// Round 3
// baseline (11284.563 us; speedup 1.0000x reference)
//
#include <hip/hip_runtime.h>
#include <cmath>

typedef __attribute__((ext_vector_type(8))) short short8;
typedef __attribute__((ext_vector_type(4))) float floatx4;
typedef unsigned long long u64;

#define GPTR(p) ((const __attribute__((address_space(1))) void*)(p))
#define LPTR(p) ((__attribute__((address_space(3))) void*)(p))

// slot barrier state (re-zeroed by cast_pack each launch)
__device__ unsigned int g_slots[64];

__device__ __forceinline__ unsigned short f2bf(float f) {
  union { float f; unsigned u; } v; v.f = f;
  unsigned r = (v.u + 0x7fffu + ((v.u >> 16) & 1u)) >> 16;
  return (unsigned short)r;
}
__device__ __forceinline__ float sigm_(float x) { return 1.0f / (1.0f + __expf(-x)); }
__device__ __forceinline__ float tanh_(float x) { return 1.0f - 2.0f / (__expf(2.0f * x) + 1.0f); }

// ---------------- cast / pack kernel ----------------
__global__ void cast_pack(const float* __restrict__ states,
                          const float* __restrict__ Win,
                          const float* __restrict__ Wih,
                          const float* __restrict__ Whh,
                          const float* __restrict__ bih,
                          const float* __restrict__ bhh,
                          unsigned short* __restrict__ sb,
                          unsigned short* __restrict__ wpb,
                          unsigned short* __restrict__ wib,
                          unsigned short* __restrict__ whb,
                          float* __restrict__ bsum) {
  if (blockIdx.x == 0 && threadIdx.x < 64) g_slots[threadIdx.x] = 0u;
  const int NS = 8388608, NW = 524288, NI = 8388608, NH = 8388608, NB = 8192;
  const int total = NS + NW + NI + NH + NB;
  for (int i = blockIdx.x * blockDim.x + threadIdx.x; i < total;
       i += gridDim.x * blockDim.x) {
    int j = i;
    if (j < NS) { sb[j] = f2bf(states[j]); continue; }
    j -= NS;
    if (j < NW) { int r = j >> 9, c = j & 511;
                  wpb[j] = (r < 960) ? f2bf(Win[r * 512 + c]) : (unsigned short)0; continue; }
    j -= NW;
    if (j < NI) { wib[j] = f2bf(Wih[j]); continue; }
    j -= NI;
    if (j < NH) { whb[j] = f2bf(Whh[j]); continue; }
    j -= NH;
    bsum[j] = bih[j] + bhh[j];
  }
}

// ---------------- m97-style bf16 GEMM, C = A(M,K) * B(N,K)^T ----------------
template <int MODE>
__global__ __launch_bounds__(256) void gemm_bt(
    const unsigned short* __restrict__ A, const unsigned short* __restrict__ B,
    int K, int N,
    float* __restrict__ outF, unsigned short* __restrict__ outH,
    const float* __restrict__ bias,
    const float* __restrict__ emb, const int* __restrict__ aidx) {
  __shared__ unsigned short As[128 * 32];
  __shared__ unsigned short Bs[128 * 32];
  const int tid = threadIdx.x;
  const int wave = tid >> 6, lane = tid & 63;
  const int quad = lane >> 4, l16 = lane & 15;
  const int wm = (wave & 1) * 64, wn = (wave >> 1) * 64;
  const int m0 = blockIdx.x * 128, n0 = blockIdx.y * 128;
  floatx4 acc[4][4] = {};
  const int r0 = tid >> 2, c0 = (tid & 3) * 8;
  const unsigned short* Ag0 = A + (size_t)(m0 + r0) * K + c0;
  const unsigned short* Ag1 = A + (size_t)(m0 + 64 + r0) * K + c0;
  const unsigned short* Bg0 = B + (size_t)(n0 + r0) * K + c0;
  const unsigned short* Bg1 = B + (size_t)(n0 + 64 + r0) * K + c0;
  for (int kt = 0; kt < K; kt += 32) {
    __builtin_amdgcn_global_load_lds(GPTR(Ag0 + kt), LPTR(&As[tid * 8]), 16, 0, 0);
    __builtin_amdgcn_global_load_lds(GPTR(Ag1 + kt), LPTR(&As[(tid + 256) * 8]), 16, 0, 0);
    __builtin_amdgcn_global_load_lds(GPTR(Bg0 + kt), LPTR(&Bs[tid * 8]), 16, 0, 0);
    __builtin_amdgcn_global_load_lds(GPTR(Bg1 + kt), LPTR(&Bs[(tid + 256) * 8]), 16, 0, 0);
    __syncthreads();
    short8 af[4], bf[4];
#pragma unroll
    for (int i = 0; i < 4; ++i)
      af[i] = *(const short8*)&As[(wm + i * 16 + l16) * 32 + quad * 8];
#pragma unroll
    for (int j = 0; j < 4; ++j)
      bf[j] = *(const short8*)&Bs[(wn + j * 16 + l16) * 32 + quad * 8];
#pragma unroll
    for (int i = 0; i < 4; ++i)
#pragma unroll
      for (int j = 0; j < 4; ++j)
        acc[i][j] = __builtin_amdgcn_mfma_f32_16x16x32_bf16(af[i], bf[j], acc[i][j], 0, 0, 0);
    __syncthreads();
  }
#pragma unroll
  for (int i = 0; i < 4; ++i) {
    const int mrow = m0 + wm + i * 16 + quad * 4;
#pragma unroll
    for (int j = 0; j < 4; ++j) {
      const int n = n0 + wn + j * 16 + l16;
#pragma unroll
      for (int r = 0; r < 4; ++r) {
        const int m = mrow + r;
        float v = acc[i][j][r];
        if (MODE == 0) {
          outF[(size_t)m * N + n] = v + bias[n];
        } else {
          float o;
          if (n < 960) { o = v + bias[n]; o = o > 0.f ? o : 0.f; }
          else         { o = emb[aidx[m] * 64 + (n - 960)]; }
          outH[(size_t)m * 1024 + n] = f2bf(o);
        }
      }
    }
  }
}

// ---------------- LSTM recurrence (one layer) ----------------
// 64 wgs x 512 threads. wg owns 16 h-cols -> 64 W_hh rows (4 gates x 16 cols), in LDS.
// h exchange: write-through agent-scope stores; reads are plain cached loads (safe:
// addresses unique per step within a kernel; dispatch-start acquire handles cross-
// kernel reuse). Barrier: FLAT — every wg's wave-0 polls all 64 slots directly
// (no go-flag: two fewer IF round-trips per step). Tight spin, no s_sleep (the
// polling wave's SIMD partner is parked at s_barrier anyway).
__global__ __launch_bounds__(512) void lstm_rec(
    const unsigned short* __restrict__ Wh,   // (4096,1024) bf16 this layer
    const float* __restrict__ xg,            // (16384,4096) fp32, bias included
    unsigned short* __restrict__ hbf,        // (16384,1024) bf16 h outputs
    float* __restrict__ hs, float* __restrict__ cs,
    float* __restrict__ rnn,                 // nullptr for layer 0
    unsigned int base)                       // epoch base (0 for layer 0, 511 for layer 1)
{
  __shared__ unsigned short Wlds[64 * 1032];   // 4 units x 16 rows, stride 1032 (pad)
  __shared__ float gbuf[4 * 16 * 33];
  const int tid = threadIdx.x;
  const int wg = blockIdx.x;
  const int J0 = wg * 16;
  const int wave = tid >> 6, lane = tid & 63, quad = lane >> 4, l16 = lane & 15;
  const int cg = wave >> 1, wh = wave & 1;   // unit (col-quad group), batch-half

  // stage W_hh slice: local row r = u*16 + (g*4+uj) <- global row g*1024 + J0 + u*4 + uj
  for (int idx = tid; idx < 64 * 128; idx += 512) {
    const int r = idx >> 7, c = (idx & 127) << 3;
    const int u = r >> 4, rr = r & 15;
    const int grow = (rr >> 2) * 1024 + J0 + u * 4 + (rr & 3);
    *(short8*)&Wlds[r * 1032 + c] = *(const short8*)&Wh[(size_t)grow * 1024 + c];
  }

  // pointwise mapping: 16 consecutive lanes = 16 consecutive cols (64B-coalesced)
  const int ub = tid >> 4;          // batch 0..31
  const int jj = tid & 15;          // col within wg slice
  const int col = J0 + jj;
  const int pu = jj >> 2, puj = jj & 3;
  float cstate = 0.f;
  const size_t xrow = (size_t)ub * 512;

  float p[4];
#pragma unroll
  for (int g = 0; g < 4; ++g) p[g] = xg[(xrow + 0) * 4096 + g * 1024 + col];
  __syncthreads();

  for (int s = 0; s < 512; ++s) {
    if (s > 0) {
      const unsigned epoch = base + (unsigned)s;
      // ---- flat device barrier (h_{s-1} visible at coherence point) ----
      asm volatile("s_waitcnt vmcnt(0)" ::: "memory");   // my h stores acked at IF
      __syncthreads();                                   // whole wg drained
      if (tid == 0)
        __hip_atomic_store(&g_slots[wg], epoch, __ATOMIC_RELAXED, __HIP_MEMORY_SCOPE_AGENT);
      // prefetch this step's xg while the barrier resolves
#pragma unroll
      for (int g = 0; g < 4; ++g) p[g] = xg[(xrow + s) * 4096 + g * 1024 + col];
      if (tid < 64) {
        // wave-0 polls ALL slots itself (no go-flag hop)
        unsigned v = __hip_atomic_load(&g_slots[tid], __ATOMIC_RELAXED, __HIP_MEMORY_SCOPE_AGENT);
        while (!__all((int)(v >= epoch)))
          v = __hip_atomic_load(&g_slots[tid], __ATOMIC_RELAXED, __HIP_MEMORY_SCOPE_AGENT);
      }
      __syncthreads();

      // ---- gates slice = h_{s-1} @ Whh_slice^T (cached A-loads, 4 chains) ----
      floatx4 a0 = {}, a1 = {}, a2 = {}, a3 = {};
      const int m = wh * 16 + l16;
      const unsigned short* Au = hbf + ((size_t)m * 512 + (s - 1)) * 1024 + quad * 8;
      const unsigned short* Brow = &Wlds[(cg * 16 + l16) * 1032 + quad * 8];
#pragma unroll
      for (int ks = 0; ks < 32; ks += 4) {
        short8 av0 = *(const short8*)&Au[ks * 32];
        short8 av1 = *(const short8*)&Au[(ks + 1) * 32];
        short8 av2 = *(const short8*)&Au[(ks + 2) * 32];
        short8 av3 = *(const short8*)&Au[(ks + 3) * 32];
        short8 bv0 = *(const short8*)&Brow[ks * 32];
        short8 bv1 = *(const short8*)&Brow[(ks + 1) * 32];
        short8 bv2 = *(const short8*)&Brow[(ks + 2) * 32];
        short8 bv3 = *(const short8*)&Brow[(ks + 3) * 32];
        a0 = __builtin_amdgcn_mfma_f32_16x16x32_bf16(av0, bv0, a0, 0, 0, 0);
        a1 = __builtin_amdgcn_mfma_f32_16x16x32_bf16(av1, bv1, a1, 0, 0, 0);
        a2 = __builtin_amdgcn_mfma_f32_16x16x32_bf16(av2, bv2, a2, 0, 0, 0);
        a3 = __builtin_amdgcn_mfma_f32_16x16x32_bf16(av3, bv3, a3, 0, 0, 0);
      }
      // C/D: col=lane&15 (=slice row n), row=quad*4+reg (=batch within half)
#pragma unroll
      for (int r = 0; r < 4; ++r)
        gbuf[cg * 528 + l16 * 33 + wh * 16 + quad * 4 + r] =
            (a0[r] + a1[r]) + (a2[r] + a3[r]);
      __syncthreads();
#pragma unroll
      for (int g = 0; g < 4; ++g)
        p[g] += gbuf[pu * 528 + (g * 4 + puj) * 33 + ub];
    }
    const float iv = sigm_(p[0]), fv = sigm_(p[1]);
    const float gv = tanh_(p[2]), ov = sigm_(p[3]);
    cstate = fv * cstate + iv * gv;
    const float hv = ov * tanh_(cstate);
    const size_t ob = (xrow + s) * 1024 + col;
    // h exchange: write-through to coherence point first (longest-latency ack)
    __hip_atomic_store(&hbf[ob], f2bf(hv), __ATOMIC_RELAXED, __HIP_MEMORY_SCOPE_AGENT);
    // pure outputs: plain cached stores (ack from local L2; flushed at kernel end)
    hs[ob] = hv;
    cs[ob] = cstate;
    if (rnn) rnn[ob] = hv;
  }
}

extern "C" void kernel_launch(void* const* d_in, const int* in_sizes, int n_in,
                              void* d_out, int out_size, void* d_ws, size_t ws_size,
                              hipStream_t stream) {
  const float* states = (const float*)d_in[0];
  const int*   aidx   = (const int*)d_in[1];
  const float* Win    = (const float*)d_in[2];
  const float* bin    = (const float*)d_in[3];
  const float* emb    = (const float*)d_in[4];
  const float* Wih    = (const float*)d_in[5];
  const float* Whh    = (const float*)d_in[6];
  const float* bih    = (const float*)d_in[7];
  const float* bhh    = (const float*)d_in[8];
  float* out = (float*)d_out;
  const size_t BSH = 32ull * 512 * 1024;
  float* rnn_out = out;
  float* hs0 = out + BSH;
  float* hs1 = out + 2 * BSH;
  float* cs0 = out + 3 * BSH;
  float* cs1 = out + 4 * BSH;

  char* w = (char*)d_ws;
  unsigned short* sb  = (unsigned short*)w; w += 16777216;   // states bf16
  unsigned short* wpb = (unsigned short*)w; w += 1048576;    // W_in padded bf16 (1024x512)
  unsigned short* wib = (unsigned short*)w; w += 16777216;   // W_ih bf16 (2 layers)
  unsigned short* whb = (unsigned short*)w; w += 16777216;   // W_hh bf16 (2 layers)
  float*          bsum= (float*)w;          w += 32768;      // b_ih+b_hh (2x4096)
  unsigned short* x0  = (unsigned short*)w; w += 33554432;   // LSTM-0 input bf16
  unsigned short* hbf = (unsigned short*)w; w += 33554432;   // per-layer h bf16
  float*          xg  = (float*)w;                           // (16384x4096) fp32

  hipLaunchKernelGGL(cast_pack, dim3(4096), dim3(256), 0, stream,
                     states, Win, Wih, Whh, bih, bhh, sb, wpb, wib, whb, bsum);

  // x0 = [relu(states@Win^T + bin), emb[idx]]  (M=16384,N=1024,K=512)
  hipLaunchKernelGGL((gemm_bt<1>), dim3(128, 8), dim3(256), 0, stream,
                     sb, wpb, 512, 1024, (float*)nullptr, x0, bin, emb, aidx);

  // xg0 = x0 @ W_ih0^T + (b_ih0 + b_hh0)
  hipLaunchKernelGGL((gemm_bt<0>), dim3(128, 32), dim3(256), 0, stream,
                     x0, wib, 1024, 4096, xg, (unsigned short*)nullptr, bsum,
                     (const float*)nullptr, (const int*)nullptr);

  // layer-0 recurrence (cooperative: guarantees co-residency of 64 wgs)
  {
    const unsigned short* whL = whb;
    const float* xgp = xg;
    unsigned short* hbfp = hbf;
    float* hsp = hs0; float* csp = cs0; float* rnnp = nullptr;
    unsigned int basev = 0u;
    void* args[] = { &whL, &xgp, &hbfp, &hsp, &csp, &rnnp, &basev };
    hipLaunchCooperativeKernel((void*)lstm_rec, dim3(64), dim3(512), args, 0, stream);
  }

  // xg1 = h0_bf16 @ W_ih1^T + (b_ih1 + b_hh1)
  hipLaunchKernelGGL((gemm_bt<0>), dim3(128, 32), dim3(256), 0, stream,
                     hbf, wib + 4194304, 1024, 4096, xg, (unsigned short*)nullptr,
                     bsum + 4096, (const float*)nullptr, (const int*)nullptr);

  // layer-1 recurrence; also writes rnn_out (epochs continue at 512)
  {
    const unsigned short* whL = whb + 4194304;
    const float* xgp = xg;
    unsigned short* hbfp = hbf;
    float* hsp = hs1; float* csp = cs1; float* rnnp = rnn_out;
    unsigned int basev = 511u;
    void* args[] = { &whL, &xgp, &hbfp, &hsp, &csp, &rnnp, &basev };
    hipLaunchCooperativeKernel((void*)lstm_rec, dim3(64), dim3(512), args, 0, stream);
  }
}

// Round 5
// 5864.775 us; speedup vs baseline: 1.9241x; 1.9241x over previous
//
#include <hip/hip_runtime.h>
#include <cmath>

typedef __attribute__((ext_vector_type(8))) short short8;
typedef __attribute__((ext_vector_type(4))) float floatx4;

#define GPTR(p) ((const __attribute__((address_space(1))) void*)(p))
#define LPTR(p) ((__attribute__((address_space(3))) void*)(p))

#define AL(p)   __hip_atomic_load((p),      __ATOMIC_RELAXED, __HIP_MEMORY_SCOPE_AGENT)
#define AS(p,v) __hip_atomic_store((p),(v), __ATOMIC_RELAXED, __HIP_MEMORY_SCOPE_AGENT)

// pipeline state (re-zeroed by cast_pack each launch)
// slots[0..63]=L0, [64..127]=xg-stream, [128..191]=L1
__device__ unsigned int g_slots[192];
__device__ unsigned int g_go0[32];   // separate lines to avoid false sharing
__device__ unsigned int g_gox[32];
__device__ unsigned int g_go1[32];

__device__ __forceinline__ unsigned short f2bf(float f) {
  union { float f; unsigned u; } v; v.f = f;
  unsigned r = (v.u + 0x7fffu + ((v.u >> 16) & 1u)) >> 16;
  return (unsigned short)r;
}
__device__ __forceinline__ float sigm_(float x) { return 1.0f / (1.0f + __expf(-x)); }
__device__ __forceinline__ float tanh_(float x) { return 1.0f - 2.0f / (__expf(2.0f * x) + 1.0f); }

// 32-chunk (K=1024) gate matvec: 4 independent MFMA chains.
__device__ __forceinline__ void mfma_k1024(const unsigned short* Au, const unsigned short* Brow,
                                           floatx4& a0, floatx4& a1, floatx4& a2, floatx4& a3) {
#pragma unroll
  for (int ks = 0; ks < 32; ks += 4) {
    short8 av0 = *(const short8*)&Au[ks * 32];
    short8 av1 = *(const short8*)&Au[(ks + 1) * 32];
    short8 av2 = *(const short8*)&Au[(ks + 2) * 32];
    short8 av3 = *(const short8*)&Au[(ks + 3) * 32];
    short8 bv0 = *(const short8*)&Brow[ks * 32];
    short8 bv1 = *(const short8*)&Brow[(ks + 1) * 32];
    short8 bv2 = *(const short8*)&Brow[(ks + 2) * 32];
    short8 bv3 = *(const short8*)&Brow[(ks + 3) * 32];
    a0 = __builtin_amdgcn_mfma_f32_16x16x32_bf16(av0, bv0, a0, 0, 0, 0);
    a1 = __builtin_amdgcn_mfma_f32_16x16x32_bf16(av1, bv1, a1, 0, 0, 0);
    a2 = __builtin_amdgcn_mfma_f32_16x16x32_bf16(av2, bv2, a2, 0, 0, 0);
    a3 = __builtin_amdgcn_mfma_f32_16x16x32_bf16(av3, bv3, a3, 0, 0, 0);
  }
}

// ---------------- cast / pack kernel ----------------
__global__ void cast_pack(const float* __restrict__ states,
                          const float* __restrict__ Win,
                          const float* __restrict__ Wih,
                          const float* __restrict__ Whh,
                          const float* __restrict__ bih,
                          const float* __restrict__ bhh,
                          unsigned short* __restrict__ sb,
                          unsigned short* __restrict__ wpb,
                          unsigned short* __restrict__ wib,
                          unsigned short* __restrict__ whb,
                          float* __restrict__ bsum) {
  if (blockIdx.x == 0) {
    if (threadIdx.x < 192) g_slots[threadIdx.x] = 0u;
    if (threadIdx.x == 192) { g_go0[0] = 0u; g_gox[0] = 0u; g_go1[0] = 0u; }
  }
  const int NS = 8388608, NW = 524288, NI = 8388608, NH = 8388608, NB = 8192;
  const int total = NS + NW + NI + NH + NB;
  for (int i = blockIdx.x * blockDim.x + threadIdx.x; i < total;
       i += gridDim.x * blockDim.x) {
    int j = i;
    if (j < NS) { sb[j] = f2bf(states[j]); continue; }
    j -= NS;
    if (j < NW) { int r = j >> 9, c = j & 511;
                  wpb[j] = (r < 960) ? f2bf(Win[r * 512 + c]) : (unsigned short)0; continue; }
    j -= NW;
    if (j < NI) { wib[j] = f2bf(Wih[j]); continue; }
    j -= NI;
    if (j < NH) { whb[j] = f2bf(Whh[j]); continue; }
    j -= NH;
    bsum[j] = bih[j] + bhh[j];
  }
}

// ---------------- m97-style bf16 GEMM, C = A(M,K) * B(N,K)^T ----------------
template <int MODE>
__global__ __launch_bounds__(256) void gemm_bt(
    const unsigned short* __restrict__ A, const unsigned short* __restrict__ B,
    int K, int N,
    float* __restrict__ outF, unsigned short* __restrict__ outH,
    const float* __restrict__ bias,
    const float* __restrict__ emb, const int* __restrict__ aidx) {
  __shared__ unsigned short As[128 * 32];
  __shared__ unsigned short Bs[128 * 32];
  const int tid = threadIdx.x;
  const int wave = tid >> 6, lane = tid & 63;
  const int quad = lane >> 4, l16 = lane & 15;
  const int wm = (wave & 1) * 64, wn = (wave >> 1) * 64;
  const int m0 = blockIdx.x * 128, n0 = blockIdx.y * 128;
  floatx4 acc[4][4] = {};
  const int r0 = tid >> 2, c0 = (tid & 3) * 8;
  const unsigned short* Ag0 = A + (size_t)(m0 + r0) * K + c0;
  const unsigned short* Ag1 = A + (size_t)(m0 + 64 + r0) * K + c0;
  const unsigned short* Bg0 = B + (size_t)(n0 + r0) * K + c0;
  const unsigned short* Bg1 = B + (size_t)(n0 + 64 + r0) * K + c0;
  for (int kt = 0; kt < K; kt += 32) {
    __builtin_amdgcn_global_load_lds(GPTR(Ag0 + kt), LPTR(&As[tid * 8]), 16, 0, 0);
    __builtin_amdgcn_global_load_lds(GPTR(Ag1 + kt), LPTR(&As[(tid + 256) * 8]), 16, 0, 0);
    __builtin_amdgcn_global_load_lds(GPTR(Bg0 + kt), LPTR(&Bs[tid * 8]), 16, 0, 0);
    __builtin_amdgcn_global_load_lds(GPTR(Bg1 + kt), LPTR(&Bs[(tid + 256) * 8]), 16, 0, 0);
    __syncthreads();
    short8 af[4], bf[4];
#pragma unroll
    for (int i = 0; i < 4; ++i)
      af[i] = *(const short8*)&As[(wm + i * 16 + l16) * 32 + quad * 8];
#pragma unroll
    for (int j = 0; j < 4; ++j)
      bf[j] = *(const short8*)&Bs[(wn + j * 16 + l16) * 32 + quad * 8];
#pragma unroll
    for (int i = 0; i < 4; ++i)
#pragma unroll
      for (int j = 0; j < 4; ++j)
        acc[i][j] = __builtin_amdgcn_mfma_f32_16x16x32_bf16(af[i], bf[j], acc[i][j], 0, 0, 0);
    __syncthreads();
  }
#pragma unroll
  for (int i = 0; i < 4; ++i) {
    const int mrow = m0 + wm + i * 16 + quad * 4;
#pragma unroll
    for (int j = 0; j < 4; ++j) {
      const int n = n0 + wn + j * 16 + l16;
#pragma unroll
      for (int r = 0; r < 4; ++r) {
        const int m = mrow + r;
        float v = acc[i][j][r];
        if (MODE == 0) {
          outF[(size_t)m * N + n] = v + bias[n];
        } else {
          float o;
          if (n < 960) { o = v + bias[n]; o = o > 0.f ? o : 0.f; }
          else         { o = emb[aidx[m] * 64 + (n - 960)]; }
          outH[(size_t)m * 1024 + n] = f2bf(o);
        }
      }
    }
  }
}

// ---------------- fused 2-layer pipelined LSTM ----------------
// 192 wgs x 512 threads, cooperative. Groups:
//   [0,64)   L0 recurrence (round-2 structure, slot0/go0 per step)
//   [64,128) xg-stream: on go0>=s+1 read h0[s] (cached, first-touch post-drain),
//            xg1 tile = h0[s] @ Wih1_slice^T + bsum1, WT-store IN PLACE over xg
//            row s (all L0 wgs consumed it before go0 reached s+1), publish gox.
//   [128,192) L1 recurrence gated on gox (xg1 read UNCACHED: this XCD may hold
//            stale cached xg0 copies of those addresses) + own go1.
// Invariant: any CACHED read's first touch of a line happens only after ALL
// producers of that line drained (full-group go-gate) — no partial-line reads.
__global__ __launch_bounds__(512) void fused_rec(
    const unsigned short* __restrict__ Wh0,
    const unsigned short* __restrict__ Wh1,
    const unsigned short* __restrict__ Wi1,
    const float* __restrict__ bsum1,     // b_ih1 + b_hh1 (4096)
    float* __restrict__ xg,              // xg0 (precomputed); rows become xg1 in place
    unsigned short* __restrict__ h0b,
    unsigned short* __restrict__ h1b,
    float* __restrict__ hs0, float* __restrict__ cs0,
    float* __restrict__ hs1, float* __restrict__ cs1,
    float* __restrict__ rnn) {
  __shared__ unsigned short Wlds[64 * 1032];   // 64 rows, stride 1032 (pad)
  __shared__ float gbuf[4 * 16 * 33];
  const int tid = threadIdx.x;
  const int wgid = blockIdx.x;
  const int wave = tid >> 6, lane = tid & 63, quad = lane >> 4, l16 = lane & 15;
  const int cg = wave >> 1, wh = wave & 1;

  if (wgid >= 64 && wgid < 128) {
    // ================= xg-stream role =================
    const int wgx = wgid - 64;
    const int J0 = wgx * 16;
    for (int idx = tid; idx < 64 * 128; idx += 512) {
      const int r = idx >> 7, c = (idx & 127) << 3;
      const int u = r >> 4, rr = r & 15;
      const int grow = (rr >> 2) * 1024 + J0 + u * 4 + (rr & 3);
      *(short8*)&Wlds[r * 1032 + c] = *(const short8*)&Wi1[(size_t)grow * 1024 + c];
    }
    __syncthreads();
    const int m = wh * 16 + l16;
    const int gcol = (l16 >> 2) * 1024 + J0 + cg * 4 + (l16 & 3);
    const float bias = bsum1[gcol];
    const unsigned short* Brow = &Wlds[(cg * 16 + l16) * 1032 + quad * 8];
    for (int s = 0; s < 512; ++s) {
      if (tid == 0) { while (AL(&g_go0[0]) < (unsigned)(s + 1)) __builtin_amdgcn_s_sleep(1); }
      __syncthreads();
      floatx4 a0 = {}, a1 = {}, a2 = {}, a3 = {};
      const unsigned short* Au = h0b + ((size_t)m * 512 + s) * 1024 + quad * 8;
      mfma_k1024(Au, Brow, a0, a1, a2, a3);
#pragma unroll
      for (int r = 0; r < 4; ++r) {
        const int b = wh * 16 + quad * 4 + r;
        AS(&xg[((size_t)b * 512 + s) * 4096 + gcol],
           (a0[r] + a1[r]) + (a2[r] + a3[r]) + bias);
      }
      asm volatile("s_waitcnt vmcnt(0)" ::: "memory");
      __syncthreads();
      if (tid == 0) AS(&g_slots[64 + wgx], (unsigned)(s + 1));
      if (wgx == 0 && tid < 64) {
        for (;;) {
          unsigned v = AL(&g_slots[64 + tid]);
          if (__all((int)(v >= (unsigned)(s + 1)))) break;
          __builtin_amdgcn_s_sleep(1);
        }
        if (tid == 0) AS(&g_gox[0], (unsigned)(s + 1));
      }
    }
    return;
  }

  // ================= recurrence role (L0 or L1) =================
  const bool isL1 = (wgid >= 128);
  const int j = isL1 ? wgid - 128 : wgid;
  const int J0 = j * 16;
  const unsigned short* Whh = isL1 ? Wh1 : Wh0;
  unsigned short* hb = isL1 ? h1b : h0b;
  float* hsO = isL1 ? hs1 : hs0;
  float* csO = isL1 ? cs1 : cs0;
  unsigned int* mySlot = &g_slots[(isL1 ? 128 : 0) + j];
  unsigned int* myGo = isL1 ? &g_go1[0] : &g_go0[0];
  const int slotBase = isL1 ? 128 : 0;

  for (int idx = tid; idx < 64 * 128; idx += 512) {
    const int r = idx >> 7, c = (idx & 127) << 3;
    const int u = r >> 4, rr = r & 15;
    const int grow = (rr >> 2) * 1024 + J0 + u * 4 + (rr & 3);
    *(short8*)&Wlds[r * 1032 + c] = *(const short8*)&Whh[(size_t)grow * 1024 + c];
  }

  const int ub = tid >> 4, jj = tid & 15;
  const int col = J0 + jj;
  const int pu = jj >> 2, puj = jj & 3;
  float cstate = 0.f;
  const size_t xrow = (size_t)ub * 512;
  float p[4];
  if (!isL1) {
#pragma unroll
    for (int g = 0; g < 4; ++g) p[g] = xg[xrow * 4096 + g * 1024 + col];
  }
  __syncthreads();

  for (int s = 0; s < 512; ++s) {
    if (isL1) {
      if (tid == 0) {
        while (AL(&g_gox[0]) < (unsigned)(s + 1) ||
               (s > 0 && AL(&g_go1[0]) < (unsigned)s))
          __builtin_amdgcn_s_sleep(1);
      }
      __syncthreads();
      // xg1 read: UNCACHED; issued early, consumed only after the gbuf phase.
#pragma unroll
      for (int g = 0; g < 4; ++g)
        p[g] = AL(&xg[(xrow + s) * 4096 + g * 1024 + col]);
    } else if (s > 0) {
      if (tid == 0) { while (AL(&g_go0[0]) < (unsigned)s) __builtin_amdgcn_s_sleep(1); }
      __syncthreads();
    }
    if (s > 0) {
      floatx4 a0 = {}, a1 = {}, a2 = {}, a3 = {};
      const int m = wh * 16 + l16;
      const unsigned short* Au = hb + ((size_t)m * 512 + (s - 1)) * 1024 + quad * 8;
      const unsigned short* Brow = &Wlds[(cg * 16 + l16) * 1032 + quad * 8];
      mfma_k1024(Au, Brow, a0, a1, a2, a3);
      // C/D: col=lane&15 (=slice row n), row=quad*4+reg (=batch within half)
#pragma unroll
      for (int r = 0; r < 4; ++r)
        gbuf[cg * 528 + l16 * 33 + wh * 16 + quad * 4 + r] =
            (a0[r] + a1[r]) + (a2[r] + a3[r]);
      __syncthreads();
#pragma unroll
      for (int g = 0; g < 4; ++g)
        p[g] += gbuf[pu * 528 + (g * 4 + puj) * 33 + ub];
    }
    const float iv = sigm_(p[0]), fv = sigm_(p[1]);
    const float gv = tanh_(p[2]), ov = sigm_(p[3]);
    cstate = fv * cstate + iv * gv;
    const float hv = ov * tanh_(cstate);
    const size_t ob = (xrow + s) * 1024 + col;
    // h exchange: write-through to coherence point, drain, publish
    AS(&hb[ob], f2bf(hv));
    asm volatile("s_waitcnt vmcnt(0)" ::: "memory");
    __syncthreads();
    if (tid == 0) AS(mySlot, (unsigned)(s + 1));
    // aux outputs off the critical path (covered by next drain / kernel end)
    hsO[ob] = hv;
    csO[ob] = cstate;
    if (isL1) rnn[ob] = hv;
    if (!isL1 && s < 511) {
#pragma unroll
      for (int g = 0; g < 4; ++g) p[g] = xg[(xrow + s + 1) * 4096 + g * 1024 + col];
    }
    if (j == 0 && tid < 64) {
      for (;;) {
        unsigned v = AL(&g_slots[slotBase + tid]);
        if (__all((int)(v >= (unsigned)(s + 1)))) break;
        __builtin_amdgcn_s_sleep(1);
      }
      if (tid == 0) AS(myGo, (unsigned)(s + 1));
    }
  }
}

extern "C" void kernel_launch(void* const* d_in, const int* in_sizes, int n_in,
                              void* d_out, int out_size, void* d_ws, size_t ws_size,
                              hipStream_t stream) {
  const float* states = (const float*)d_in[0];
  const int*   aidx   = (const int*)d_in[1];
  const float* Win    = (const float*)d_in[2];
  const float* bin    = (const float*)d_in[3];
  const float* emb    = (const float*)d_in[4];
  const float* Wih    = (const float*)d_in[5];
  const float* Whh    = (const float*)d_in[6];
  const float* bih    = (const float*)d_in[7];
  const float* bhh    = (const float*)d_in[8];
  float* out = (float*)d_out;
  const size_t BSH = 32ull * 512 * 1024;
  float* rnn_out = out;
  float* hs0 = out + BSH;
  float* hs1 = out + 2 * BSH;
  float* cs0 = out + 3 * BSH;
  float* cs1 = out + 4 * BSH;

  char* w = (char*)d_ws;
  unsigned short* sb  = (unsigned short*)w; w += 16777216;   // states bf16
  unsigned short* wpb = (unsigned short*)w; w += 1048576;    // W_in padded bf16 (1024x512)
  unsigned short* wib = (unsigned short*)w; w += 16777216;   // W_ih bf16 (2 layers)
  unsigned short* whb = (unsigned short*)w; w += 16777216;   // W_hh bf16 (2 layers)
  float*          bsum= (float*)w;          w += 32768;      // b_ih+b_hh (2x4096)
  unsigned short* x0  = (unsigned short*)w; w += 33554432;   // LSTM-0 input bf16; REUSED as h1 bf16
  unsigned short* hbf0= (unsigned short*)w; w += 33554432;   // layer-0 h bf16
  float*          xg  = (float*)w;                           // (16384x4096) fp32, in-place xg0->xg1

  hipLaunchKernelGGL(cast_pack, dim3(4096), dim3(256), 0, stream,
                     states, Win, Wih, Whh, bih, bhh, sb, wpb, wib, whb, bsum);

  // x0 = [relu(states@Win^T + bin), emb[idx]]  (M=16384,N=1024,K=512)
  hipLaunchKernelGGL((gemm_bt<1>), dim3(128, 8), dim3(256), 0, stream,
                     sb, wpb, 512, 1024, (float*)nullptr, x0, bin, emb, aidx);

  // xg0 = x0 @ W_ih0^T + (b_ih0 + b_hh0)
  hipLaunchKernelGGL((gemm_bt<0>), dim3(128, 32), dim3(256), 0, stream,
                     x0, wib, 1024, 4096, xg, (unsigned short*)nullptr, bsum,
                     (const float*)nullptr, (const int*)nullptr);

  // fused pipelined recurrence: L0 || xg-stream(W_ih1, bsum1) || L1.
  // x0 buffer is dead after the xg0 GEMM -> reused as h1 bf16 storage.
  {
    const unsigned short* wh0 = whb;
    const unsigned short* wh1 = whb + 4194304;
    const unsigned short* wi1 = wib + 4194304;
    const float* bs1 = bsum + 4096;
    float* xgp = xg;
    unsigned short* h0p = hbf0;
    unsigned short* h1p = x0;
    float* hs0p = hs0; float* cs0p = cs0;
    float* hs1p = hs1; float* cs1p = cs1;
    float* rnnp = rnn_out;
    void* args[] = { &wh0, &wh1, &wi1, &bs1, &xgp, &h0p, &h1p,
                     &hs0p, &cs0p, &hs1p, &cs1p, &rnnp };
    hipLaunchCooperativeKernel((void*)fused_rec, dim3(192), dim3(512), args, 0, stream);
  }
}